// Round 1
// baseline (2433.381 us; speedup 1.0000x reference)
//
#include <hip/hip_runtime.h>
#include <math.h>

#define D_MODEL 1024
#define N_HEADS 16
#define HDIM    64
#define D_FF    4096
#define SEQ     2048
#define BATCH   2
#define NTOK    (SEQ*BATCH)   // 4096 tokens

// ---------------------------------------------------------------------------
// block-wide sum reduction (256 threads = 4 waves of 64)
// ---------------------------------------------------------------------------
__device__ __forceinline__ float block_sum_256(float v, volatile float* red) {
#pragma unroll
    for (int off = 32; off >= 1; off >>= 1) v += __shfl_xor(v, off, 64);
    int wid = threadIdx.x >> 6;
    __syncthreads();                       // protect red reuse across calls
    if ((threadIdx.x & 63) == 0) red[wid] = v;
    __syncthreads();
    return red[0] + red[1] + red[2] + red[3];
}

// ---------------------------------------------------------------------------
// GEMM: Y[N][M] = X[N][K] @ W[M][K]^T + bias[M]
// N, M multiples of 64; K multiple of 16.
// 64x64 tile / block of 256 threads, 4x4 microtile, fp32.
// ---------------------------------------------------------------------------
__global__ __launch_bounds__(256) void gemm_bias_kernel(
    const float* __restrict__ X, const float* __restrict__ W,
    const float* __restrict__ bias, float* __restrict__ Y,
    int N, int M, int K)
{
    __shared__ float As[16][68];   // [k][i], +4 pad keeps 16B align & banks
    __shared__ float Bs[16][68];   // [k][j]
    const int i0 = blockIdx.y * 64;
    const int j0 = blockIdx.x * 64;
    const int t  = threadIdx.x;
    const int tx = t & 15, ty = t >> 4;
    const int lr = t >> 2;           // 0..63 (row within tile for loads)
    const int lk = (t & 3) * 4;      // 0,4,8,12 (k offset for loads)

    float acc[4][4] = {};

    for (int k0 = 0; k0 < K; k0 += 16) {
        float4 av = *(const float4*)&X[(size_t)(i0 + lr) * K + k0 + lk];
        float4 bv = *(const float4*)&W[(size_t)(j0 + lr) * K + k0 + lk];
        __syncthreads();             // previous iteration finished reading LDS
        As[lk+0][lr] = av.x; As[lk+1][lr] = av.y;
        As[lk+2][lr] = av.z; As[lk+3][lr] = av.w;
        Bs[lk+0][lr] = bv.x; Bs[lk+1][lr] = bv.y;
        Bs[lk+2][lr] = bv.z; Bs[lk+3][lr] = bv.w;
        __syncthreads();
#pragma unroll
        for (int kk = 0; kk < 16; ++kk) {
            float4 a = *(const float4*)&As[kk][ty * 4];
            float4 b = *(const float4*)&Bs[kk][tx * 4];
            float ar[4] = {a.x, a.y, a.z, a.w};
            float br[4] = {b.x, b.y, b.z, b.w};
#pragma unroll
            for (int r = 0; r < 4; ++r)
#pragma unroll
                for (int c = 0; c < 4; ++c)
                    acc[r][c] = fmaf(ar[r], br[c], acc[r][c]);
        }
    }

    float4 bb = *(const float4*)&bias[j0 + tx * 4];
#pragma unroll
    for (int r = 0; r < 4; ++r) {
        float4 o;
        o.x = acc[r][0] + bb.x; o.y = acc[r][1] + bb.y;
        o.z = acc[r][2] + bb.z; o.w = acc[r][3] + bb.w;
        *(float4*)&Y[(size_t)(i0 + ty * 4 + r) * M + j0 + tx * 4] = o;
    }
}

// ---------------------------------------------------------------------------
// In-place row normalization: y = y / (||y|| + 1e-8), optional relu AFTER.
// One block (256 thr) per row of length M (1024 or 4096).
// ---------------------------------------------------------------------------
template<int M, bool RELU>
__global__ __launch_bounds__(256) void rownorm_kernel(float* __restrict__ Y)
{
    __shared__ float red[4];
    const int row = blockIdx.x;
    const int t = threadIdx.x;
    constexpr int NV = M / 1024;        // float4s per thread (1 or 4)
    const size_t base = (size_t)row * M;
    float4 vv[NV];
    float ss = 0.f;
#pragma unroll
    for (int u = 0; u < NV; ++u) {
        vv[u] = *(const float4*)&Y[base + (size_t)(u * 256 + t) * 4];
        ss += vv[u].x*vv[u].x + vv[u].y*vv[u].y + vv[u].z*vv[u].z + vv[u].w*vv[u].w;
    }
    ss = block_sum_256(ss, red);
    float sc = 1.f / (sqrtf(ss) + 1e-8f);
#pragma unroll
    for (int u = 0; u < NV; ++u) {
        float4 o;
        o.x = vv[u].x * sc; o.y = vv[u].y * sc;
        o.z = vv[u].z * sc; o.w = vv[u].w * sc;
        if (RELU) {
            o.x = fmaxf(o.x, 0.f); o.y = fmaxf(o.y, 0.f);
            o.z = fmaxf(o.z, 0.f); o.w = fmaxf(o.w, 0.f);
        }
        *(float4*)&Y[base + (size_t)(u * 256 + t) * 4] = o;
    }
}

// ---------------------------------------------------------------------------
// Flash-style UHG attention.
// q,k,v: (S,B,D_MODEL) rows already unit-normalized over the FULL 1024 dim.
// score(i,j) = -sqrt(max(0, 1 - dot^2/(qn_i*kn_j + 1e-8))), softmax over j,
// out(s,b,h*64+d) = sum_j p * v.
// Block: 256 thr; 32 queries x 64-key tiles; grid (S/32, H, B).
// ---------------------------------------------------------------------------
__global__ __launch_bounds__(256) void attn_kernel(
    const float* __restrict__ q, const float* __restrict__ k,
    const float* __restrict__ v, float* __restrict__ out)
{
    __shared__ float Qs[32][68];
    __shared__ float Ks[64][68];
    __shared__ float Vs[64][68];
    __shared__ float Ps[32][68];
    __shared__ float qn_s[32];
    __shared__ float kn_s[64];

    const int h = blockIdx.y, b = blockIdx.z;
    const int iq0 = blockIdx.x * 32;
    const int t = threadIdx.x;
    const int d  = t & 63;
    const int r0 = t >> 6;              // 0..3
    const size_t cbase = (size_t)h * HDIM;

    // stage Q tile (once)
#pragma unroll
    for (int rr = 0; rr < 8; ++rr) {
        int i = rr * 4 + r0;
        Qs[i][d] = q[((size_t)(iq0 + i) * BATCH + b) * D_MODEL + cbase + d];
    }
    __syncthreads();
    if (t < 32) {
        float s = 0.f;
#pragma unroll
        for (int dd = 0; dd < 64; dd += 4) {
            float4 qv = *(const float4*)&Qs[t][dd];
            s += qv.x*qv.x + qv.y*qv.y + qv.z*qv.z + qv.w*qv.w;
        }
        qn_s[t] = s;
    }

    const int i  = t >> 3;              // owned query row 0..31
    const int dg = t & 7;               // dim group
    const int d0 = dg * 8;
    float O[8] = {};
    float m_run = -1e30f, l_run = 0.f;

    for (int jt = 0; jt < SEQ / 64; ++jt) {
        const int jk0 = jt * 64;
        __syncthreads();                // prev PV / qn done
#pragma unroll
        for (int rr = 0; rr < 16; ++rr) {
            int j = rr * 4 + r0;
            size_t ga = ((size_t)(jk0 + j) * BATCH + b) * D_MODEL + cbase + d;
            Ks[j][d] = k[ga];
            Vs[j][d] = v[ga];
        }
        __syncthreads();
        if (t < 64) {
            float s = 0.f;
#pragma unroll
            for (int dd = 0; dd < 64; dd += 4) {
                float4 kv = *(const float4*)&Ks[t][dd];
                s += kv.x*kv.x + kv.y*kv.y + kv.z*kv.z + kv.w*kv.w;
            }
            kn_s[t] = s;
        }
        __syncthreads();

        // 8 scores per thread: jj = dg + 8*st
        float sreg[8];
        const float qn_i = qn_s[i];
#pragma unroll
        for (int st = 0; st < 8; ++st) {
            const int jj = dg + st * 8;
            float dot = 0.f;
#pragma unroll
            for (int dd = 0; dd < 64; dd += 4) {
                float4 qv = *(const float4*)&Qs[i][dd];
                float4 kv = *(const float4*)&Ks[jj][dd];
                dot += qv.x*kv.x + qv.y*kv.y + qv.z*kv.z + qv.w*kv.w;
            }
            float den = qn_i * kn_s[jj] + 1e-8f;
            float quad = fmaxf(0.f, 1.f - dot * dot / den);
            sreg[st] = -sqrtf(quad);
        }

        // online softmax over the 8-lane row group
        float tmax = sreg[0];
#pragma unroll
        for (int st = 1; st < 8; ++st) tmax = fmaxf(tmax, sreg[st]);
        tmax = fmaxf(tmax, __shfl_xor(tmax, 1, 8));
        tmax = fmaxf(tmax, __shfl_xor(tmax, 2, 8));
        tmax = fmaxf(tmax, __shfl_xor(tmax, 4, 8));
        float m_new = fmaxf(m_run, tmax);
        float scale = __expf(m_run - m_new);
        float psum = 0.f;
#pragma unroll
        for (int st = 0; st < 8; ++st) {
            float p = __expf(sreg[st] - m_new);
            Ps[i][dg + st * 8] = p;
            psum += p;
        }
        psum += __shfl_xor(psum, 1, 8);
        psum += __shfl_xor(psum, 2, 8);
        psum += __shfl_xor(psum, 4, 8);
        l_run = l_run * scale + psum;
        m_run = m_new;
#pragma unroll
        for (int r = 0; r < 8; ++r) O[r] *= scale;
        __syncthreads();                // Ps ready

        // PV accumulate: O[i][d0..d0+7] += sum_jj p * V[jj][d]
#pragma unroll 8
        for (int jj = 0; jj < 64; ++jj) {
            float p = Ps[i][jj];
            float4 v0 = *(const float4*)&Vs[jj][d0];
            float4 v1 = *(const float4*)&Vs[jj][d0 + 4];
            O[0] = fmaf(p, v0.x, O[0]); O[1] = fmaf(p, v0.y, O[1]);
            O[2] = fmaf(p, v0.z, O[2]); O[3] = fmaf(p, v0.w, O[3]);
            O[4] = fmaf(p, v1.x, O[4]); O[5] = fmaf(p, v1.y, O[5]);
            O[6] = fmaf(p, v1.z, O[6]); O[7] = fmaf(p, v1.w, O[7]);
        }
    }

    const float inv_l = 1.f / l_run;
#pragma unroll
    for (int r = 0; r < 8; ++r) O[r] *= inv_l;
    size_t ob = ((size_t)(iq0 + i) * BATCH + b) * D_MODEL + cbase + d0;
    float4 o0 = {O[0], O[1], O[2], O[3]};
    float4 o1 = {O[4], O[5], O[6], O[7]};
    *(float4*)&out[ob]     = o0;
    *(float4*)&out[ob + 4] = o1;
}

// ---------------------------------------------------------------------------
// y = LayerNorm(A + B; ddof=1, eps=1e-5) * g + beta ; if FINAL: y /= ||y||
// one block per row of 1024.
// ---------------------------------------------------------------------------
__global__ __launch_bounds__(256) void add_ln_kernel(
    const float* __restrict__ A, const float* __restrict__ Bp,
    const float* __restrict__ g, const float* __restrict__ beta,
    float* __restrict__ Y, int finalnorm)
{
    __shared__ float red[4];
    const int row = blockIdx.x;
    const int t = threadIdx.x;
    const size_t base = (size_t)row * D_MODEL + t * 4;

    float4 a = *(const float4*)&A[base];
    float4 c = *(const float4*)&Bp[base];
    float4 vx = {a.x + c.x, a.y + c.y, a.z + c.z, a.w + c.w};

    float s = vx.x + vx.y + vx.z + vx.w;
    s = block_sum_256(s, red);
    float mean = s * (1.f / 1024.f);

    float4 dv = {vx.x - mean, vx.y - mean, vx.z - mean, vx.w - mean};
    float s2 = dv.x*dv.x + dv.y*dv.y + dv.z*dv.z + dv.w*dv.w;
    s2 = block_sum_256(s2, red);
    float rstd = rsqrtf(s2 * (1.f / 1023.f) + 1e-5f);

    float4 gg = *(const float4*)&g[t * 4];
    float4 bb = *(const float4*)&beta[t * 4];
    float4 y;
    y.x = dv.x * rstd * gg.x + bb.x;
    y.y = dv.y * rstd * gg.y + bb.y;
    y.z = dv.z * rstd * gg.z + bb.z;
    y.w = dv.w * rstd * gg.w + bb.w;

    if (finalnorm) {
        float s3 = y.x*y.x + y.y*y.y + y.z*y.z + y.w*y.w;
        s3 = block_sum_256(s3, red);
        float inv = 1.f / sqrtf(s3);
        y.x *= inv; y.y *= inv; y.z *= inv; y.w *= inv;
    }
    *(float4*)&Y[base] = y;
}

// ---------------------------------------------------------------------------
extern "C" void kernel_launch(void* const* d_in, const int* in_sizes, int n_in,
                              void* d_out, int out_size, void* d_ws, size_t ws_size,
                              hipStream_t stream)
{
    const float* src  = (const float*)d_in[0];
    const float* wq   = (const float*)d_in[1];
    const float* bq   = (const float*)d_in[2];
    const float* wk   = (const float*)d_in[3];
    const float* bk   = (const float*)d_in[4];
    const float* wv   = (const float*)d_in[5];
    const float* bv   = (const float*)d_in[6];
    const float* wo   = (const float*)d_in[7];
    const float* bo   = (const float*)d_in[8];
    const float* w1   = (const float*)d_in[9];
    const float* b1   = (const float*)d_in[10];
    const float* w2   = (const float*)d_in[11];
    const float* b2   = (const float*)d_in[12];
    const float* g1   = (const float*)d_in[13];
    const float* be1  = (const float*)d_in[14];
    const float* g2   = (const float*)d_in[15];
    const float* be2  = (const float*)d_in[16];

    float* ws = (float*)d_ws;
    const size_t M4 = (size_t)4 * 1024 * 1024;    // 4M floats = 16MB
    float* qb = ws;            // [0,   4M)   q   -> later x
    float* kb = ws + M4;       // [4M,  8M)   k   -> later h (spans 4M..20M)
    float* vb = ws + 2 * M4;   // [8M, 12M)   v
    float* ab = ws + 3 * M4;   // [12M,16M)   attn out (pre-wo)
    float* pb = ws + 4 * M4;   // [16M,20M)   attn projection
    float* xb = qb;            // x after LN1 (q dead after attention)
    float* hb = kb;            // h: 16M floats, k/v/ab/pb dead by then
    float* ffb  = (float*)d_out;   // ff staged in d_out
    float* outp = (float*)d_out;

    dim3 blk(256);
    dim3 g1024(D_MODEL / 64, NTOK / 64);   // (16,64)
    dim3 g4096(D_FF / 64, NTOK / 64);      // (64,64)

    // q, k, v projections + project-to-sphere
    gemm_bias_kernel<<<g1024, blk, 0, stream>>>(src, wq, bq, qb, NTOK, D_MODEL, D_MODEL);
    rownorm_kernel<D_MODEL, false><<<NTOK, blk, 0, stream>>>(qb);
    gemm_bias_kernel<<<g1024, blk, 0, stream>>>(src, wk, bk, kb, NTOK, D_MODEL, D_MODEL);
    rownorm_kernel<D_MODEL, false><<<NTOK, blk, 0, stream>>>(kb);
    gemm_bias_kernel<<<g1024, blk, 0, stream>>>(src, wv, bv, vb, NTOK, D_MODEL, D_MODEL);
    rownorm_kernel<D_MODEL, false><<<NTOK, blk, 0, stream>>>(vb);

    // attention
    attn_kernel<<<dim3(SEQ / 32, N_HEADS, BATCH), blk, 0, stream>>>(qb, kb, vb, ab);

    // output projection
    gemm_bias_kernel<<<g1024, blk, 0, stream>>>(ab, wo, bo, pb, NTOK, D_MODEL, D_MODEL);
    rownorm_kernel<D_MODEL, false><<<NTOK, blk, 0, stream>>>(pb);

    // x = LN(src + attn_out)
    add_ln_kernel<<<NTOK, blk, 0, stream>>>(src, pb, g1, be1, xb, 0);

    // FFN
    gemm_bias_kernel<<<g4096, blk, 0, stream>>>(xb, w1, b1, hb, NTOK, D_FF, D_MODEL);
    rownorm_kernel<D_FF, true><<<NTOK, blk, 0, stream>>>(hb);
    gemm_bias_kernel<<<g1024, blk, 0, stream>>>(hb, w2, b2, ffb, NTOK, D_MODEL, D_FF);
    rownorm_kernel<D_MODEL, false><<<NTOK, blk, 0, stream>>>(ffb);

    // x = LN(x + ff); x /= ||x||
    add_ln_kernel<<<NTOK, blk, 0, stream>>>(xb, ffb, g2, be2, outp, 1);
}

// Round 3
// 1291.235 us; speedup vs baseline: 1.8845x; 1.8845x over previous
//
#include <hip/hip_runtime.h>
#include <math.h>

#define D_MODEL 1024
#define N_HEADS 16
#define HDIM    64
#define D_FF    4096
#define SEQ     2048
#define BATCH   2
#define NTOK    (SEQ*BATCH)   // 4096 tokens

typedef __attribute__((ext_vector_type(8))) short short8;
typedef __attribute__((ext_vector_type(4))) float f32x4;
typedef __attribute__((ext_vector_type(4))) unsigned short us4;

// round-to-nearest-even f32 -> bf16
__device__ __forceinline__ unsigned short f2bf(float f) {
    union { float f; unsigned u; } x; x.f = f;
    unsigned r = x.u + 0x7fffu + ((x.u >> 16) & 1u);
    return (unsigned short)(r >> 16);
}

typedef __attribute__((address_space(1))) const unsigned short g_u16;
typedef __attribute__((address_space(3))) unsigned short l_u16;
__device__ __forceinline__ void gload_lds16(const unsigned short* g, unsigned short* l) {
    __builtin_amdgcn_global_load_lds((g_u16*)g, (l_u16*)l, 16, 0, 0);
}

// ---------------------------------------------------------------------------
// block-wide sum reduction (256 threads = 4 waves of 64)
// ---------------------------------------------------------------------------
__device__ __forceinline__ float block_sum_256(float v, volatile float* red) {
#pragma unroll
    for (int off = 32; off >= 1; off >>= 1) v += __shfl_xor(v, off, 64);
    int wid = threadIdx.x >> 6;
    __syncthreads();                       // protect red reuse across calls
    if ((threadIdx.x & 63) == 0) red[wid] = v;
    __syncthreads();
    return red[0] + red[1] + red[2] + red[3];
}

// ---------------------------------------------------------------------------
// fp32 -> bf16 convert (n4 = number of float4 groups)
// ---------------------------------------------------------------------------
__global__ __launch_bounds__(256) void convert_bf16_kernel(
    const float* __restrict__ in, unsigned short* __restrict__ out, int n4)
{
    int i = blockIdx.x * 256 + threadIdx.x;
    if (i >= n4) return;
    float4 v = *(const float4*)&in[(size_t)i * 4];
    us4 o = { f2bf(v.x), f2bf(v.y), f2bf(v.z), f2bf(v.w) };
    *(us4*)&out[(size_t)i * 4] = o;
}

// ---------------------------------------------------------------------------
// bf16 MFMA GEMM: Y[N][M] = A[N][lda(bf16)] @ W[M][K]^T + bias[M], fp32 out.
// 128x128 tile / 256 threads (4 waves, 2x2), BK=32, mfma 16x16x32 bf16,
// global_load_lds width 16 staging (m97 structure). N,M mult of 128, K of 32.
// ---------------------------------------------------------------------------
__global__ __launch_bounds__(256) void gemm_bf16_kernel(
    const unsigned short* __restrict__ A,
    const unsigned short* __restrict__ W,
    const float* __restrict__ bias,
    float* __restrict__ Y,
    int M, int K, int lda)
{
    __shared__ unsigned short As[128 * 32];
    __shared__ unsigned short Bs[128 * 32];

    const int t    = threadIdx.x;
    const int lane = t & 63;
    const int w    = t >> 6;
    const int wr   = w >> 1, wc = w & 1;
    const int i0   = blockIdx.y * 128;
    const int j0   = blockIdx.x * 128;
    const int lrow = lane & 15;
    const int lk   = (lane >> 4) * 8;

    f32x4 zero4 = {0.f, 0.f, 0.f, 0.f};
    f32x4 acc[4][4];
#pragma unroll
    for (int mi = 0; mi < 4; ++mi)
#pragma unroll
        for (int ni = 0; ni < 4; ++ni) acc[mi][ni] = zero4;

    for (int k0 = 0; k0 < K; k0 += 32) {
        // stage A,B tiles: 8 KB each; per wave 2 instr per tile, lane-linear LDS
#pragma unroll
        for (int s = 0; s < 2; ++s) {
            int u     = s * 4 + w;          // 0..7
            int chunk = u * 64 + lane;      // 0..511 (16B chunks)
            int row   = chunk >> 2;         // 0..127
            int kc    = (chunk & 3) * 8;    // bf16 col offset
            gload_lds16(&A[(size_t)(i0 + row) * lda + k0 + kc], &As[u * 512]);
            gload_lds16(&W[(size_t)(j0 + row) * (size_t)K + k0 + kc], &Bs[u * 512]);
        }
        __syncthreads();    // compiler drains vmcnt(0) before barrier

        short8 af[4], bf[4];
#pragma unroll
        for (int mi = 0; mi < 4; ++mi)
            af[mi] = *(const short8*)&As[(wr * 64 + mi * 16 + lrow) * 32 + lk];
#pragma unroll
        for (int ni = 0; ni < 4; ++ni)
            bf[ni] = *(const short8*)&Bs[(wc * 64 + ni * 16 + lrow) * 32 + lk];
#pragma unroll
        for (int mi = 0; mi < 4; ++mi)
#pragma unroll
            for (int ni = 0; ni < 4; ++ni)
                acc[mi][ni] = __builtin_amdgcn_mfma_f32_16x16x32_bf16(
                    af[mi], bf[ni], acc[mi][ni], 0, 0, 0);
        __syncthreads();    // all waves done reading before next overwrite
    }

    // epilogue: C/D layout col=lane&15, row=(lane>>4)*4+reg
    const int orow = (lane >> 4) * 4;
    const int ocol = lane & 15;
#pragma unroll
    for (int ni = 0; ni < 4; ++ni) {
        int c = j0 + wc * 64 + ni * 16 + ocol;
        float bv = bias[c];
#pragma unroll
        for (int mi = 0; mi < 4; ++mi) {
            int rbase = i0 + wr * 64 + mi * 16 + orow;
#pragma unroll
            for (int r = 0; r < 4; ++r)
                Y[(size_t)(rbase + r) * M + c] = acc[mi][ni][r] + bv;
        }
    }
}

// ---------------------------------------------------------------------------
// In-place row normalization: y = y / (||y|| + 1e-8), optional relu AFTER.
// BF16OUT: write bf16 in-place at the row start (stride stays M floats).
// One block (256 thr) per row of length M (1024 or 4096).
// ---------------------------------------------------------------------------
template<int M, bool RELU, bool BF16OUT>
__global__ __launch_bounds__(256) void rownorm_kernel(float* __restrict__ Y)
{
    __shared__ float red[4];
    const int row = blockIdx.x;
    const int t = threadIdx.x;
    constexpr int NV = M / 1024;        // float4s per thread (1 or 4)
    const size_t base = (size_t)row * M;
    float4 vv[NV];
    float ss = 0.f;
#pragma unroll
    for (int u = 0; u < NV; ++u) {
        vv[u] = *(const float4*)&Y[base + (size_t)(u * 256 + t) * 4];
        ss += vv[u].x*vv[u].x + vv[u].y*vv[u].y + vv[u].z*vv[u].z + vv[u].w*vv[u].w;
    }
    ss = block_sum_256(ss, red);        // barrier: all reads done before writes
    float sc = 1.f / (sqrtf(ss) + 1e-8f);
#pragma unroll
    for (int u = 0; u < NV; ++u) {
        float4 o;
        o.x = vv[u].x * sc; o.y = vv[u].y * sc;
        o.z = vv[u].z * sc; o.w = vv[u].w * sc;
        if (RELU) {
            o.x = fmaxf(o.x, 0.f); o.y = fmaxf(o.y, 0.f);
            o.z = fmaxf(o.z, 0.f); o.w = fmaxf(o.w, 0.f);
        }
        if (BF16OUT) {
            unsigned short* yb = (unsigned short*)&Y[base];
            us4 ob = { f2bf(o.x), f2bf(o.y), f2bf(o.z), f2bf(o.w) };
            *(us4*)&yb[(size_t)(u * 256 + t) * 4] = ob;
        } else {
            *(float4*)&Y[base + (size_t)(u * 256 + t) * 4] = o;
        }
    }
}

// ---------------------------------------------------------------------------
// Flash-style UHG attention (fp32).
// ---------------------------------------------------------------------------
__global__ __launch_bounds__(256) void attn_kernel(
    const float* __restrict__ q, const float* __restrict__ k,
    const float* __restrict__ v, float* __restrict__ out)
{
    __shared__ float Qs[32][68];
    __shared__ float Ks[64][68];
    __shared__ float Vs[64][68];
    __shared__ float Ps[32][68];
    __shared__ float qn_s[32];
    __shared__ float kn_s[64];

    const int h = blockIdx.y, b = blockIdx.z;
    const int iq0 = blockIdx.x * 32;
    const int t = threadIdx.x;
    const int d  = t & 63;
    const int r0 = t >> 6;              // 0..3
    const size_t cbase = (size_t)h * HDIM;

#pragma unroll
    for (int rr = 0; rr < 8; ++rr) {
        int i = rr * 4 + r0;
        Qs[i][d] = q[((size_t)(iq0 + i) * BATCH + b) * D_MODEL + cbase + d];
    }
    __syncthreads();
    if (t < 32) {
        float s = 0.f;
#pragma unroll
        for (int dd = 0; dd < 64; dd += 4) {
            float4 qv = *(const float4*)&Qs[t][dd];
            s += qv.x*qv.x + qv.y*qv.y + qv.z*qv.z + qv.w*qv.w;
        }
        qn_s[t] = s;
    }

    const int i  = t >> 3;              // owned query row 0..31
    const int dg = t & 7;               // dim group
    const int d0 = dg * 8;
    float O[8] = {};
    float m_run = -1e30f, l_run = 0.f;

    for (int jt = 0; jt < SEQ / 64; ++jt) {
        const int jk0 = jt * 64;
        __syncthreads();
#pragma unroll
        for (int rr = 0; rr < 16; ++rr) {
            int j = rr * 4 + r0;
            size_t ga = ((size_t)(jk0 + j) * BATCH + b) * D_MODEL + cbase + d;
            Ks[j][d] = k[ga];
            Vs[j][d] = v[ga];
        }
        __syncthreads();
        if (t < 64) {
            float s = 0.f;
#pragma unroll
            for (int dd = 0; dd < 64; dd += 4) {
                float4 kv = *(const float4*)&Ks[t][dd];
                s += kv.x*kv.x + kv.y*kv.y + kv.z*kv.z + kv.w*kv.w;
            }
            kn_s[t] = s;
        }
        __syncthreads();

        float sreg[8];
        const float qn_i = qn_s[i];
#pragma unroll
        for (int st = 0; st < 8; ++st) {
            const int jj = dg + st * 8;
            float dot = 0.f;
#pragma unroll
            for (int dd = 0; dd < 64; dd += 4) {
                float4 qv = *(const float4*)&Qs[i][dd];
                float4 kv = *(const float4*)&Ks[jj][dd];
                dot += qv.x*kv.x + qv.y*kv.y + qv.z*kv.z + qv.w*kv.w;
            }
            float den = qn_i * kn_s[jj] + 1e-8f;
            float quad = fmaxf(0.f, 1.f - dot * dot / den);
            sreg[st] = -sqrtf(quad);
        }

        float tmax = sreg[0];
#pragma unroll
        for (int st = 1; st < 8; ++st) tmax = fmaxf(tmax, sreg[st]);
        tmax = fmaxf(tmax, __shfl_xor(tmax, 1, 8));
        tmax = fmaxf(tmax, __shfl_xor(tmax, 2, 8));
        tmax = fmaxf(tmax, __shfl_xor(tmax, 4, 8));
        float m_new = fmaxf(m_run, tmax);
        float scale = __expf(m_run - m_new);
        float psum = 0.f;
#pragma unroll
        for (int st = 0; st < 8; ++st) {
            float p = __expf(sreg[st] - m_new);
            Ps[i][dg + st * 8] = p;
            psum += p;
        }
        psum += __shfl_xor(psum, 1, 8);
        psum += __shfl_xor(psum, 2, 8);
        psum += __shfl_xor(psum, 4, 8);
        l_run = l_run * scale + psum;
        m_run = m_new;
#pragma unroll
        for (int r = 0; r < 8; ++r) O[r] *= scale;
        __syncthreads();

#pragma unroll 8
        for (int jj = 0; jj < 64; ++jj) {
            float p = Ps[i][jj];
            float4 v0 = *(const float4*)&Vs[jj][d0];
            float4 v1 = *(const float4*)&Vs[jj][d0 + 4];
            O[0] = fmaf(p, v0.x, O[0]); O[1] = fmaf(p, v0.y, O[1]);
            O[2] = fmaf(p, v0.z, O[2]); O[3] = fmaf(p, v0.w, O[3]);
            O[4] = fmaf(p, v1.x, O[4]); O[5] = fmaf(p, v1.y, O[5]);
            O[6] = fmaf(p, v1.z, O[6]); O[7] = fmaf(p, v1.w, O[7]);
        }
    }

    const float inv_l = 1.f / l_run;
#pragma unroll
    for (int r = 0; r < 8; ++r) O[r] *= inv_l;
    size_t ob = ((size_t)(iq0 + i) * BATCH + b) * D_MODEL + cbase + d0;
    float4 o0 = {O[0], O[1], O[2], O[3]};
    float4 o1 = {O[4], O[5], O[6], O[7]};
    *(float4*)&out[ob]     = o0;
    *(float4*)&out[ob + 4] = o1;
}

// ---------------------------------------------------------------------------
// y = LayerNorm(A + B; ddof=1, eps=1e-5) * g + beta ; if FINAL: y /= ||y||
// optional bf16 copy to Yb (dense, stride D_MODEL). one block per row.
// ---------------------------------------------------------------------------
__global__ __launch_bounds__(256) void add_ln_kernel(
    const float* __restrict__ A, const float* __restrict__ Bp,
    const float* __restrict__ g, const float* __restrict__ beta,
    float* __restrict__ Y, unsigned short* __restrict__ Yb, int finalnorm)
{
    __shared__ float red[4];
    const int row = blockIdx.x;
    const int t = threadIdx.x;
    const size_t base = (size_t)row * D_MODEL + t * 4;

    float4 a = *(const float4*)&A[base];
    float4 c = *(const float4*)&Bp[base];
    float4 vx = {a.x + c.x, a.y + c.y, a.z + c.z, a.w + c.w};

    float s = vx.x + vx.y + vx.z + vx.w;
    s = block_sum_256(s, red);
    float mean = s * (1.f / 1024.f);

    float4 dv = {vx.x - mean, vx.y - mean, vx.z - mean, vx.w - mean};
    float s2 = dv.x*dv.x + dv.y*dv.y + dv.z*dv.z + dv.w*dv.w;
    s2 = block_sum_256(s2, red);
    float rstd = rsqrtf(s2 * (1.f / 1023.f) + 1e-5f);

    float4 gg = *(const float4*)&g[t * 4];
    float4 bb = *(const float4*)&beta[t * 4];
    float4 y;
    y.x = dv.x * rstd * gg.x + bb.x;
    y.y = dv.y * rstd * gg.y + bb.y;
    y.z = dv.z * rstd * gg.z + bb.z;
    y.w = dv.w * rstd * gg.w + bb.w;

    if (finalnorm) {
        float s3 = y.x*y.x + y.y*y.y + y.z*y.z + y.w*y.w;
        s3 = block_sum_256(s3, red);
        float inv = 1.f / sqrtf(s3);
        y.x *= inv; y.y *= inv; y.z *= inv; y.w *= inv;
    }
    *(float4*)&Y[base] = y;
    if (Yb) {
        us4 ob = { f2bf(y.x), f2bf(y.y), f2bf(y.z), f2bf(y.w) };
        *(us4*)&Yb[base] = ob;
    }
}

// ---------------------------------------------------------------------------
extern "C" void kernel_launch(void* const* d_in, const int* in_sizes, int n_in,
                              void* d_out, int out_size, void* d_ws, size_t ws_size,
                              hipStream_t stream)
{
    const float* src  = (const float*)d_in[0];
    const float* wq   = (const float*)d_in[1];
    const float* bq   = (const float*)d_in[2];
    const float* wk   = (const float*)d_in[3];
    const float* bk   = (const float*)d_in[4];
    const float* wv   = (const float*)d_in[5];
    const float* bv   = (const float*)d_in[6];
    const float* wo   = (const float*)d_in[7];
    const float* bo   = (const float*)d_in[8];
    const float* w1   = (const float*)d_in[9];
    const float* b1   = (const float*)d_in[10];
    const float* w2   = (const float*)d_in[11];
    const float* b2   = (const float*)d_in[12];
    const float* g1   = (const float*)d_in[13];
    const float* be1  = (const float*)d_in[14];
    const float* g2   = (const float*)d_in[15];
    const float* be2  = (const float*)d_in[16];

    char* wsb = (char*)d_ws;
    const size_t MB = (size_t)1 << 20;
    float* qb = (float*)(wsb + 0 * MB);      // [0,16MB)   q -> later x (fp32)
    float* kb = (float*)(wsb + 16 * MB);     // [16,32MB)  k ; hb spans [16,80MB)
    float* vb = (float*)(wsb + 32 * MB);     // [32,48MB)  v
    float* ab = (float*)(wsb + 48 * MB);     // [48,64MB)  attn out, then pb
    float* pb = ab;
    float* xb = qb;
    float* hb = kb;                          // 16M floats = [16,80MB)
    unsigned short* srcb = (unsigned short*)(wsb + 64 * MB);  // 8MB (dead before FFN1)
    unsigned short* abb  = (unsigned short*)(wsb + 72 * MB);  // 8MB (dead before FFN1)
    unsigned short* wqb  = (unsigned short*)(wsb + 80 * MB);  // 2MB
    unsigned short* wkb  = (unsigned short*)(wsb + 82 * MB);
    unsigned short* wvb  = (unsigned short*)(wsb + 84 * MB);
    unsigned short* wob  = (unsigned short*)(wsb + 86 * MB);
    unsigned short* w1b  = (unsigned short*)(wsb + 88 * MB);  // 8MB
    unsigned short* w2b  = (unsigned short*)(wsb + 96 * MB);  // 8MB
    unsigned short* xbb  = (unsigned short*)(wsb + 104 * MB); // 8MB  (peak 112MB)
    unsigned short* hbb  = (unsigned short*)hb;               // in-place, stride 8192
    float* ffb  = (float*)d_out;
    float* outp = (float*)d_out;

    dim3 blk(256);
    dim3 gP(D_MODEL / 128, NTOK / 128);      // (8,32)  projections
    dim3 gF(D_FF / 128, NTOK / 128);         // (32,32) FFN1

    // ---- fp32 -> bf16 converts (weights + src, every call) ----
    convert_bf16_kernel<<<(NTOK*D_MODEL/4 + 255)/256, blk, 0, stream>>>(src, srcb, NTOK*D_MODEL/4);
    convert_bf16_kernel<<<(D_MODEL*D_MODEL/4 + 255)/256, blk, 0, stream>>>(wq, wqb, D_MODEL*D_MODEL/4);
    convert_bf16_kernel<<<(D_MODEL*D_MODEL/4 + 255)/256, blk, 0, stream>>>(wk, wkb, D_MODEL*D_MODEL/4);
    convert_bf16_kernel<<<(D_MODEL*D_MODEL/4 + 255)/256, blk, 0, stream>>>(wv, wvb, D_MODEL*D_MODEL/4);
    convert_bf16_kernel<<<(D_MODEL*D_MODEL/4 + 255)/256, blk, 0, stream>>>(wo, wob, D_MODEL*D_MODEL/4);
    convert_bf16_kernel<<<(D_FF*D_MODEL/4 + 255)/256, blk, 0, stream>>>(w1, w1b, D_FF*D_MODEL/4);
    convert_bf16_kernel<<<(D_MODEL*D_FF/4 + 255)/256, blk, 0, stream>>>(w2, w2b, D_MODEL*D_FF/4);

    // ---- q, k, v projections + project-to-sphere ----
    gemm_bf16_kernel<<<gP, blk, 0, stream>>>(srcb, wqb, bq, qb, D_MODEL, D_MODEL, D_MODEL);
    rownorm_kernel<D_MODEL, false, false><<<NTOK, blk, 0, stream>>>(qb);
    gemm_bf16_kernel<<<gP, blk, 0, stream>>>(srcb, wkb, bk, kb, D_MODEL, D_MODEL, D_MODEL);
    rownorm_kernel<D_MODEL, false, false><<<NTOK, blk, 0, stream>>>(kb);
    gemm_bf16_kernel<<<gP, blk, 0, stream>>>(srcb, wvb, bv, vb, D_MODEL, D_MODEL, D_MODEL);
    rownorm_kernel<D_MODEL, false, false><<<NTOK, blk, 0, stream>>>(vb);

    // ---- attention (fp32) ----
    attn_kernel<<<dim3(SEQ / 32, N_HEADS, BATCH), blk, 0, stream>>>(qb, kb, vb, ab);
    convert_bf16_kernel<<<(NTOK*D_MODEL/4 + 255)/256, blk, 0, stream>>>(ab, abb, NTOK*D_MODEL/4);

    // ---- output projection ----
    gemm_bf16_kernel<<<gP, blk, 0, stream>>>(abb, wob, bo, pb, D_MODEL, D_MODEL, D_MODEL);
    rownorm_kernel<D_MODEL, false, false><<<NTOK, blk, 0, stream>>>(pb);

    // ---- x = LN(src + attn_out), fp32 + bf16 copy ----
    add_ln_kernel<<<NTOK, blk, 0, stream>>>(src, pb, g1, be1, xb, xbb, 0);

    // ---- FFN ----
    gemm_bf16_kernel<<<gF, blk, 0, stream>>>(xbb, w1b, b1, hb, D_FF, D_MODEL, D_MODEL);
    rownorm_kernel<D_FF, true, true><<<NTOK, blk, 0, stream>>>(hb);   // bf16 in-place
    gemm_bf16_kernel<<<gP, blk, 0, stream>>>(hbb, w2b, b2, ffb, D_MODEL, D_FF, 2 * D_FF);
    rownorm_kernel<D_MODEL, false, false><<<NTOK, blk, 0, stream>>>(ffb);

    // ---- x = LN(x + ff); x /= ||x|| ----
    add_ln_kernel<<<NTOK, blk, 0, stream>>>(xb, ffb, g2, be2, outp, nullptr, 1);
}

// Round 7
// 669.567 us; speedup vs baseline: 3.6343x; 1.9285x over previous
//
#include <hip/hip_runtime.h>
#include <math.h>

#define D_MODEL 1024
#define N_HEADS 16
#define HDIM    64
#define D_FF    4096
#define SEQ     2048
#define BATCH   2
#define NTOK    (SEQ*BATCH)   // 4096 tokens

typedef __attribute__((ext_vector_type(8))) short short8;
typedef __attribute__((ext_vector_type(4))) float f32x4;
typedef __attribute__((ext_vector_type(4))) unsigned short us4;

// round-to-nearest-even f32 -> bf16
__device__ __forceinline__ unsigned short f2bf(float f) {
    union { float f; unsigned u; } x; x.f = f;
    unsigned r = x.u + 0x7fffu + ((x.u >> 16) & 1u);
    return (unsigned short)(r >> 16);
}
__device__ __forceinline__ float bf2f(unsigned short u) {
    union { unsigned u; float f; } x; x.u = ((unsigned)u) << 16; return x.f;
}

typedef __attribute__((address_space(1))) const unsigned short g_u16;
typedef __attribute__((address_space(3))) unsigned short l_u16;
__device__ __forceinline__ void gload_lds16(const unsigned short* g, unsigned short* l) {
    __builtin_amdgcn_global_load_lds((g_u16*)g, (l_u16*)l, 16, 0, 0);
}

// ---------------------------------------------------------------------------
// block-wide sum reduction (256 threads = 4 waves of 64)
// ---------------------------------------------------------------------------
__device__ __forceinline__ float block_sum_256(float v, volatile float* red) {
#pragma unroll
    for (int off = 32; off >= 1; off >>= 1) v += __shfl_xor(v, off, 64);
    int wid = threadIdx.x >> 6;
    __syncthreads();                       // protect red reuse across calls
    if ((threadIdx.x & 63) == 0) red[wid] = v;
    __syncthreads();
    return red[0] + red[1] + red[2] + red[3];
}

// ---------------------------------------------------------------------------
// fp32 -> bf16 convert (n4 = number of float4 groups)
// ---------------------------------------------------------------------------
__global__ __launch_bounds__(256) void convert_bf16_kernel(
    const float* __restrict__ in, unsigned short* __restrict__ out, int n4)
{
    int i = blockIdx.x * 256 + threadIdx.x;
    if (i >= n4) return;
    float4 v = *(const float4*)&in[(size_t)i * 4];
    us4 o = { f2bf(v.x), f2bf(v.y), f2bf(v.z), f2bf(v.w) };
    *(us4*)&out[(size_t)i * 4] = o;
}

// ---------------------------------------------------------------------------
// bf16 MFMA GEMM: Y[N][M] = A[N][lda(bf16)] @ W[M][K]^T + bias[M], fp32 out.
// 128x128 tile / 256 threads (4 waves, 2x2), BK=32, mfma 16x16x32 bf16,
// global_load_lds width 16 staging (m97 structure). N,M mult of 128, K of 32.
// ---------------------------------------------------------------------------
__global__ __launch_bounds__(256) void gemm_bf16_kernel(
    const unsigned short* __restrict__ A,
    const unsigned short* __restrict__ W,
    const float* __restrict__ bias,
    float* __restrict__ Y,
    int M, int K, int lda)
{
    __shared__ unsigned short As[128 * 32];
    __shared__ unsigned short Bs[128 * 32];

    const int t    = threadIdx.x;
    const int lane = t & 63;
    const int w    = t >> 6;
    const int wr   = w >> 1, wc = w & 1;
    const int i0   = blockIdx.y * 128;
    const int j0   = blockIdx.x * 128;
    const int lrow = lane & 15;
    const int lk   = (lane >> 4) * 8;

    f32x4 zero4 = {0.f, 0.f, 0.f, 0.f};
    f32x4 acc[4][4];
#pragma unroll
    for (int mi = 0; mi < 4; ++mi)
#pragma unroll
        for (int ni = 0; ni < 4; ++ni) acc[mi][ni] = zero4;

    for (int k0 = 0; k0 < K; k0 += 32) {
#pragma unroll
        for (int s = 0; s < 2; ++s) {
            int u     = s * 4 + w;          // 0..7
            int chunk = u * 64 + lane;      // 0..511 (16B chunks)
            int row   = chunk >> 2;         // 0..127
            int kc    = (chunk & 3) * 8;    // bf16 col offset
            gload_lds16(&A[(size_t)(i0 + row) * lda + k0 + kc], &As[u * 512]);
            gload_lds16(&W[(size_t)(j0 + row) * (size_t)K + k0 + kc], &Bs[u * 512]);
        }
        __syncthreads();

        short8 af[4], bf[4];
#pragma unroll
        for (int mi = 0; mi < 4; ++mi)
            af[mi] = *(const short8*)&As[(wr * 64 + mi * 16 + lrow) * 32 + lk];
#pragma unroll
        for (int ni = 0; ni < 4; ++ni)
            bf[ni] = *(const short8*)&Bs[(wc * 64 + ni * 16 + lrow) * 32 + lk];
#pragma unroll
        for (int mi = 0; mi < 4; ++mi)
#pragma unroll
            for (int ni = 0; ni < 4; ++ni)
                acc[mi][ni] = __builtin_amdgcn_mfma_f32_16x16x32_bf16(
                    af[mi], bf[ni], acc[mi][ni], 0, 0, 0);
        __syncthreads();
    }

    const int orow = (lane >> 4) * 4;
    const int ocol = lane & 15;
#pragma unroll
    for (int ni = 0; ni < 4; ++ni) {
        int c = j0 + wc * 64 + ni * 16 + ocol;
        float bv = bias[c];
#pragma unroll
        for (int mi = 0; mi < 4; ++mi) {
            int rbase = i0 + wr * 64 + mi * 16 + orow;
#pragma unroll
            for (int r = 0; r < 4; ++r)
                Y[(size_t)(rbase + r) * M + c] = acc[mi][ni][r] + bv;
        }
    }
}

// ---------------------------------------------------------------------------
// In-place row normalization: y = y / (||y|| + 1e-8), optional relu AFTER.
// BF16OUT: write bf16 in-place at the row start (stride stays M floats).
// ---------------------------------------------------------------------------
template<int M, bool RELU, bool BF16OUT>
__global__ __launch_bounds__(256) void rownorm_kernel(float* __restrict__ Y)
{
    __shared__ float red[4];
    const int row = blockIdx.x;
    const int t = threadIdx.x;
    constexpr int NV = M / 1024;        // float4s per thread (1 or 4)
    const size_t base = (size_t)row * M;
    float4 vv[NV];
    float ss = 0.f;
#pragma unroll
    for (int u = 0; u < NV; ++u) {
        vv[u] = *(const float4*)&Y[base + (size_t)(u * 256 + t) * 4];
        ss += vv[u].x*vv[u].x + vv[u].y*vv[u].y + vv[u].z*vv[u].z + vv[u].w*vv[u].w;
    }
    ss = block_sum_256(ss, red);        // barrier: all reads done before writes
    float sc = 1.f / (sqrtf(ss) + 1e-8f);
#pragma unroll
    for (int u = 0; u < NV; ++u) {
        float4 o;
        o.x = vv[u].x * sc; o.y = vv[u].y * sc;
        o.z = vv[u].z * sc; o.w = vv[u].w * sc;
        if (RELU) {
            o.x = fmaxf(o.x, 0.f); o.y = fmaxf(o.y, 0.f);
            o.z = fmaxf(o.z, 0.f); o.w = fmaxf(o.w, 0.f);
        }
        if (BF16OUT) {
            unsigned short* yb = (unsigned short*)&Y[base];
            us4 ob = { f2bf(o.x), f2bf(o.y), f2bf(o.z), f2bf(o.w) };
            *(us4*)&yb[(size_t)(u * 256 + t) * 4] = ob;
        } else {
            *(float4*)&Y[base + (size_t)(u * 256 + t) * 4] = o;
        }
    }
}

// ---------------------------------------------------------------------------
// MFMA UHG flash attention. q,k,v: bf16 written in-place over fp32 buffers
// (row stride 2048 u16), rows unit-normalized over full 1024 dims.
// score(i,j) = -sqrt(max(0, qn*kn+eps - dot^2)/(qn*kn+eps)); softmax; out=PV.
// Block: 256 thr (4 waves), 128 Q-rows for one (h,b); KV tiles of 64.
// out: bf16 [NTOK][1024] dense. Grid (S/128, H, B).
// ---------------------------------------------------------------------------
__global__ __launch_bounds__(256) void attn_mfma_kernel(
    const unsigned short* __restrict__ q,
    const unsigned short* __restrict__ k,
    const unsigned short* __restrict__ v,
    unsigned short* __restrict__ out)
{
    __shared__ unsigned short Qs[128 * 72];   // [qrow][dim], pad 72 (2-way max)
    __shared__ unsigned short Ks[64 * 72];    // [key][dim]
    __shared__ unsigned short Vt[64 * 72];    // [dim][key] (transposed at stage)
    __shared__ unsigned short Ps[4][32 * 72]; // per-wave P [qrow][key]
    __shared__ float qn_s[128];
    __shared__ float kn_s[64];

    const int h = blockIdx.y, b = blockIdx.z;
    const int iq0 = blockIdx.x * 128;
    const int t = threadIdx.x;
    const int lane = t & 63;
    const int w = t >> 6;
    const int lrow = lane & 15;
    const int lk = (lane >> 4) * 8;
    const int g = lane >> 4;
    const int c = lane & 15;
    const int cb = h * HDIM;

    // ---- stage Q tile (128 rows, 8 thr/row, 4 passes) ----
    {
        const int rl = t >> 3, ch = (t & 7) * 8;
#pragma unroll
        for (int p = 0; p < 4; ++p) {
            int row = p * 32 + rl;
            size_t ga = (size_t)((iq0 + row) * BATCH + b) * 2048 + cb + ch;
            *(short8*)&Qs[row * 72 + ch] = *(const short8*)&q[ga];
        }
    }
    __syncthreads();
    // ---- qn from bf16 (consistent with MFMA dots): 2 thr/row, 32 dims ----
    {
        const int row = t >> 1, half = (t & 1) * 32;
        float s = 0.f;
#pragma unroll
        for (int dd = 0; dd < 32; dd += 8) {
            short8 x = *(const short8*)&Qs[row * 72 + half + dd];
#pragma unroll
            for (int e = 0; e < 8; ++e) {
                float f = bf2f((unsigned short)x[e]); s += f * f;
            }
        }
        s += __shfl_xor(s, 1, 64);
        if ((t & 1) == 0) qn_s[row] = s;
    }

    f32x4 zero4 = {0.f, 0.f, 0.f, 0.f};
    f32x4 acc_o[2][4];
    float m_run[2][4], l_run[2][4];
#pragma unroll
    for (int mi = 0; mi < 2; ++mi)
#pragma unroll
        for (int r = 0; r < 4; ++r) { m_run[mi][r] = -1e30f; l_run[mi][r] = 0.f; }
#pragma unroll
    for (int mi = 0; mi < 2; ++mi)
#pragma unroll
        for (int ni = 0; ni < 4; ++ni) acc_o[mi][ni] = zero4;

    for (int jt = 0; jt < SEQ / 64; ++jt) {
        const int jk0 = jt * 64;
        __syncthreads();    // prev tile's MFMA reads + kn/qn reads done
        // ---- stage K (64 rows, 8 thr/row, 2 passes) ----
        {
            const int rl = t >> 3, ch = (t & 7) * 8;
#pragma unroll
            for (int p = 0; p < 2; ++p) {
                int row = p * 32 + rl;
                size_t ga = (size_t)((jk0 + row) * BATCH + b) * 2048 + cb + ch;
                *(short8*)&Ks[row * 72 + ch] = *(const short8*)&k[ga];
            }
        }
        // ---- stage V transposed: lane owns key=t&31, dim-chunk=t>>5 ----
        {
            const int key0 = t & 31, chs = (t >> 5) * 8;
#pragma unroll
            for (int p = 0; p < 2; ++p) {
                int key = p * 32 + key0;
                size_t ga = (size_t)((jk0 + key) * BATCH + b) * 2048 + cb + chs;
                short8 x = *(const short8*)&v[ga];
#pragma unroll
                for (int e = 0; e < 8; ++e)
                    Vt[(chs + e) * 72 + key] = (unsigned short)x[e];
            }
        }
        __syncthreads();    // staging visible
        // ---- kn: 4 thr/row, 16 dims each ----
        {
            const int row = t >> 2, qd = (t & 3) * 16;
            float s = 0.f;
#pragma unroll
            for (int dd = 0; dd < 16; dd += 8) {
                short8 x = *(const short8*)&Ks[row * 72 + qd + dd];
#pragma unroll
                for (int e = 0; e < 8; ++e) {
                    float f = bf2f((unsigned short)x[e]); s += f * f;
                }
            }
            s += __shfl_xor(s, 1, 64);
            s += __shfl_xor(s, 2, 64);
            if ((t & 3) == 0) kn_s[row] = s;
        }
        __syncthreads();    // kn visible

        // ---- QK^T: wave w owns Q rows w*32..w*32+31 ----
        f32x4 sc[2][4];
#pragma unroll
        for (int mi = 0; mi < 2; ++mi)
#pragma unroll
            for (int ni = 0; ni < 4; ++ni) sc[mi][ni] = zero4;
#pragma unroll
        for (int ks = 0; ks < 2; ++ks) {
            short8 aq[2], bk_[4];
#pragma unroll
            for (int mi = 0; mi < 2; ++mi)
                aq[mi] = *(const short8*)&Qs[(w * 32 + mi * 16 + lrow) * 72 + ks * 32 + lk];
#pragma unroll
            for (int ni = 0; ni < 4; ++ni)
                bk_[ni] = *(const short8*)&Ks[(ni * 16 + lrow) * 72 + ks * 32 + lk];
#pragma unroll
            for (int mi = 0; mi < 2; ++mi)
#pragma unroll
                for (int ni = 0; ni < 4; ++ni)
                    sc[mi][ni] = __builtin_amdgcn_mfma_f32_16x16x32_bf16(
                        aq[mi], bk_[ni], sc[mi][ni], 0, 0, 0);
        }

        // ---- score transform + online softmax (row = mi*16+g*4+r) ----
#pragma unroll
        for (int mi = 0; mi < 2; ++mi) {
#pragma unroll
            for (int r = 0; r < 4; ++r) {
                const int rowl = w * 32 + mi * 16 + g * 4 + r;
                const float qn_i = qn_s[rowl];
                float sv[4];
#pragma unroll
                for (int ni = 0; ni < 4; ++ni) {
                    float dot = sc[mi][ni][r];
                    float den = qn_i * kn_s[ni * 16 + c] + 1e-8f;
                    float quad = fmaxf(den - dot * dot, 0.f);
                    sv[ni] = -sqrtf(quad) * rsqrtf(den);
                }
                float tmax = fmaxf(fmaxf(sv[0], sv[1]), fmaxf(sv[2], sv[3]));
                tmax = fmaxf(tmax, __shfl_xor(tmax, 1, 16));
                tmax = fmaxf(tmax, __shfl_xor(tmax, 2, 16));
                tmax = fmaxf(tmax, __shfl_xor(tmax, 4, 16));
                tmax = fmaxf(tmax, __shfl_xor(tmax, 8, 16));
                float m_new = fmaxf(m_run[mi][r], tmax);
                float esc = __expf(m_run[mi][r] - m_new);
                float psum = 0.f;
#pragma unroll
                for (int ni = 0; ni < 4; ++ni) {
                    float p = __expf(sv[ni] - m_new);
                    Ps[w][(mi * 16 + g * 4 + r) * 72 + ni * 16 + c] = f2bf(p);
                    psum += p;
                }
                psum += __shfl_xor(psum, 1, 16);
                psum += __shfl_xor(psum, 2, 16);
                psum += __shfl_xor(psum, 4, 16);
                psum += __shfl_xor(psum, 8, 16);
                l_run[mi][r] = l_run[mi][r] * esc + psum;
                m_run[mi][r] = m_new;
#pragma unroll
                for (int ni = 0; ni < 4; ++ni) acc_o[mi][ni][r] *= esc;
            }
        }

        // ---- PV: O += P @ V (A=own-wave P, B=Vt rows = dims) ----
#pragma unroll
        for (int ks = 0; ks < 2; ++ks) {
            short8 ap[2], bv_[4];
#pragma unroll
            for (int mi = 0; mi < 2; ++mi)
                ap[mi] = *(const short8*)&Ps[w][(mi * 16 + lrow) * 72 + ks * 32 + lk];
#pragma unroll
            for (int ni = 0; ni < 4; ++ni)
                bv_[ni] = *(const short8*)&Vt[(ni * 16 + lrow) * 72 + ks * 32 + lk];
#pragma unroll
            for (int mi = 0; mi < 2; ++mi)
#pragma unroll
                for (int ni = 0; ni < 4; ++ni)
                    acc_o[mi][ni] = __builtin_amdgcn_mfma_f32_16x16x32_bf16(
                        ap[mi], bv_[ni], acc_o[mi][ni], 0, 0, 0);
        }
    }

    // ---- epilogue: divide by l, write bf16 to out [NTOK][1024] ----
#pragma unroll
    for (int mi = 0; mi < 2; ++mi)
#pragma unroll
        for (int r = 0; r < 4; ++r) {
            float inv = 1.f / l_run[mi][r];
            int qs = iq0 + w * 32 + mi * 16 + g * 4 + r;
            size_t ob = (size_t)(qs * BATCH + b) * 1024 + cb;
#pragma unroll
            for (int ni = 0; ni < 4; ++ni)
                out[ob + ni * 16 + c] = f2bf(acc_o[mi][ni][r] * inv);
        }
}

// ---------------------------------------------------------------------------
// y = LayerNorm(A + B; ddof=1, eps=1e-5) * g + beta ; if FINAL: y /= ||y||
// optional bf16 copy to Yb (dense, stride D_MODEL). one block per row.
// ---------------------------------------------------------------------------
__global__ __launch_bounds__(256) void add_ln_kernel(
    const float* __restrict__ A, const float* __restrict__ Bp,
    const float* __restrict__ g, const float* __restrict__ beta,
    float* __restrict__ Y, unsigned short* __restrict__ Yb, int finalnorm)
{
    __shared__ float red[4];
    const int row = blockIdx.x;
    const int t = threadIdx.x;
    const size_t base = (size_t)row * D_MODEL + t * 4;

    float4 a = *(const float4*)&A[base];
    float4 c = *(const float4*)&Bp[base];
    float4 vx = {a.x + c.x, a.y + c.y, a.z + c.z, a.w + c.w};

    float s = vx.x + vx.y + vx.z + vx.w;
    s = block_sum_256(s, red);
    float mean = s * (1.f / 1024.f);

    float4 dv = {vx.x - mean, vx.y - mean, vx.z - mean, vx.w - mean};
    float s2 = dv.x*dv.x + dv.y*dv.y + dv.z*dv.z + dv.w*dv.w;
    s2 = block_sum_256(s2, red);
    float rstd = rsqrtf(s2 * (1.f / 1023.f) + 1e-5f);

    float4 gg = *(const float4*)&g[t * 4];
    float4 bb = *(const float4*)&beta[t * 4];
    float4 y;
    y.x = dv.x * rstd * gg.x + bb.x;
    y.y = dv.y * rstd * gg.y + bb.y;
    y.z = dv.z * rstd * gg.z + bb.z;
    y.w = dv.w * rstd * gg.w + bb.w;

    if (finalnorm) {
        float s3 = y.x*y.x + y.y*y.y + y.z*y.z + y.w*y.w;
        s3 = block_sum_256(s3, red);
        float inv = 1.f / sqrtf(s3);
        y.x *= inv; y.y *= inv; y.z *= inv; y.w *= inv;
    }
    *(float4*)&Y[base] = y;
    if (Yb) {
        us4 ob = { f2bf(y.x), f2bf(y.y), f2bf(y.z), f2bf(y.w) };
        *(us4*)&Yb[base] = ob;
    }
}

// ---------------------------------------------------------------------------
extern "C" void kernel_launch(void* const* d_in, const int* in_sizes, int n_in,
                              void* d_out, int out_size, void* d_ws, size_t ws_size,
                              hipStream_t stream)
{
    const float* src  = (const float*)d_in[0];
    const float* wq   = (const float*)d_in[1];
    const float* bq   = (const float*)d_in[2];
    const float* wk   = (const float*)d_in[3];
    const float* bk   = (const float*)d_in[4];
    const float* wv   = (const float*)d_in[5];
    const float* bv   = (const float*)d_in[6];
    const float* wo   = (const float*)d_in[7];
    const float* bo   = (const float*)d_in[8];
    const float* w1   = (const float*)d_in[9];
    const float* b1   = (const float*)d_in[10];
    const float* w2   = (const float*)d_in[11];
    const float* b2   = (const float*)d_in[12];
    const float* g1   = (const float*)d_in[13];
    const float* be1  = (const float*)d_in[14];
    const float* g2   = (const float*)d_in[15];
    const float* be2  = (const float*)d_in[16];

    char* wsb = (char*)d_ws;
    const size_t MB = (size_t)1 << 20;
    float* qb = (float*)(wsb + 0 * MB);      // q (bf16 in-place) -> later x fp32
    float* kb = (float*)(wsb + 16 * MB);     // k ; hb spans [16,80MB)
    float* vb = (float*)(wsb + 32 * MB);     // v
    float* pb = (float*)(wsb + 48 * MB);     // wo projection fp32
    float* xb = qb;
    float* hb = kb;                          // [16,80MB) fp32 h
    unsigned short* srcb = (unsigned short*)(wsb + 64 * MB);  // 8MB (dead before FFN1)
    unsigned short* abb  = (unsigned short*)(wsb + 72 * MB);  // 8MB attn-out bf16 (dead before FFN1)
    unsigned short* wqb  = (unsigned short*)(wsb + 80 * MB);
    unsigned short* wkb  = (unsigned short*)(wsb + 82 * MB);
    unsigned short* wvb  = (unsigned short*)(wsb + 84 * MB);
    unsigned short* wob  = (unsigned short*)(wsb + 86 * MB);
    unsigned short* w1b  = (unsigned short*)(wsb + 88 * MB);  // 8MB
    unsigned short* w2b  = (unsigned short*)(wsb + 96 * MB);  // 8MB
    unsigned short* xbb  = (unsigned short*)(wsb + 104 * MB); // 8MB  (peak 112MB)
    unsigned short* hbb  = (unsigned short*)hb;               // in-place, stride 8192
    unsigned short* qb16 = (unsigned short*)qb;               // in-place, stride 2048
    unsigned short* kb16 = (unsigned short*)kb;
    unsigned short* vb16 = (unsigned short*)vb;
    float* ffb  = (float*)d_out;
    float* outp = (float*)d_out;

    dim3 blk(256);
    dim3 gP(D_MODEL / 128, NTOK / 128);      // (8,32)  projections
    dim3 gF(D_FF / 128, NTOK / 128);         // (32,32) FFN1

    // ---- fp32 -> bf16 converts (weights + src) ----
    convert_bf16_kernel<<<(NTOK*D_MODEL/4 + 255)/256, blk, 0, stream>>>(src, srcb, NTOK*D_MODEL/4);
    convert_bf16_kernel<<<(D_MODEL*D_MODEL/4 + 255)/256, blk, 0, stream>>>(wq, wqb, D_MODEL*D_MODEL/4);
    convert_bf16_kernel<<<(D_MODEL*D_MODEL/4 + 255)/256, blk, 0, stream>>>(wk, wkb, D_MODEL*D_MODEL/4);
    convert_bf16_kernel<<<(D_MODEL*D_MODEL/4 + 255)/256, blk, 0, stream>>>(wv, wvb, D_MODEL*D_MODEL/4);
    convert_bf16_kernel<<<(D_MODEL*D_MODEL/4 + 255)/256, blk, 0, stream>>>(wo, wob, D_MODEL*D_MODEL/4);
    convert_bf16_kernel<<<(D_FF*D_MODEL/4 + 255)/256, blk, 0, stream>>>(w1, w1b, D_FF*D_MODEL/4);
    convert_bf16_kernel<<<(D_MODEL*D_FF/4 + 255)/256, blk, 0, stream>>>(w2, w2b, D_MODEL*D_FF/4);

    // ---- q, k, v projections + project-to-sphere (bf16 in-place out) ----
    gemm_bf16_kernel<<<gP, blk, 0, stream>>>(srcb, wqb, bq, qb, D_MODEL, D_MODEL, D_MODEL);
    rownorm_kernel<D_MODEL, false, true><<<NTOK, blk, 0, stream>>>(qb);
    gemm_bf16_kernel<<<gP, blk, 0, stream>>>(srcb, wkb, bk, kb, D_MODEL, D_MODEL, D_MODEL);
    rownorm_kernel<D_MODEL, false, true><<<NTOK, blk, 0, stream>>>(kb);
    gemm_bf16_kernel<<<gP, blk, 0, stream>>>(srcb, wvb, bv, vb, D_MODEL, D_MODEL, D_MODEL);
    rownorm_kernel<D_MODEL, false, true><<<NTOK, blk, 0, stream>>>(vb);

    // ---- attention (bf16 MFMA), writes bf16 directly ----
    attn_mfma_kernel<<<dim3(SEQ / 128, N_HEADS, BATCH), blk, 0, stream>>>(qb16, kb16, vb16, abb);

    // ---- output projection ----
    gemm_bf16_kernel<<<gP, blk, 0, stream>>>(abb, wob, bo, pb, D_MODEL, D_MODEL, D_MODEL);
    rownorm_kernel<D_MODEL, false, false><<<NTOK, blk, 0, stream>>>(pb);

    // ---- x = LN(src + attn_out), fp32 + bf16 copy ----
    add_ln_kernel<<<NTOK, blk, 0, stream>>>(src, pb, g1, be1, xb, xbb, 0);

    // ---- FFN ----
    gemm_bf16_kernel<<<gF, blk, 0, stream>>>(xbb, w1b, b1, hb, D_FF, D_MODEL, D_MODEL);
    rownorm_kernel<D_FF, true, true><<<NTOK, blk, 0, stream>>>(hb);   // bf16 in-place
    gemm_bf16_kernel<<<gP, blk, 0, stream>>>(hbb, w2b, b2, ffb, D_MODEL, D_FF, 2 * D_FF);
    rownorm_kernel<D_MODEL, false, false><<<NTOK, blk, 0, stream>>>(ffb);

    // ---- x = LN(x + ff); x /= ||x|| ----
    add_ln_kernel<<<NTOK, blk, 0, stream>>>(xb, ffb, g2, be2, outp, nullptr, 1);
}

// Round 9
// 659.707 us; speedup vs baseline: 3.6886x; 1.0149x over previous
//
#include <hip/hip_runtime.h>
#include <math.h>

#define D_MODEL 1024
#define N_HEADS 16
#define HDIM    64
#define D_FF    4096
#define SEQ     2048
#define BATCH   2
#define NTOK    (SEQ*BATCH)   // 4096 tokens

typedef __attribute__((ext_vector_type(8))) short short8;
typedef __attribute__((ext_vector_type(4))) float f32x4;
typedef __attribute__((ext_vector_type(4))) unsigned short us4;

// round-to-nearest-even f32 -> bf16
__device__ __forceinline__ unsigned short f2bf(float f) {
    union { float f; unsigned u; } x; x.f = f;
    unsigned r = x.u + 0x7fffu + ((x.u >> 16) & 1u);
    return (unsigned short)(r >> 16);
}
__device__ __forceinline__ float bf2f(unsigned short u) {
    union { unsigned u; float f; } x; x.u = ((unsigned)u) << 16; return x.f;
}

typedef __attribute__((address_space(1))) const unsigned short g_u16;
typedef __attribute__((address_space(3))) unsigned short l_u16;
__device__ __forceinline__ void gload_lds16(const unsigned short* g, unsigned short* l) {
    __builtin_amdgcn_global_load_lds((g_u16*)g, (l_u16*)l, 16, 0, 0);
}

// ---------------------------------------------------------------------------
// block-wide sum reduction (256 threads = 4 waves of 64)
// ---------------------------------------------------------------------------
__device__ __forceinline__ float block_sum_256(float v, volatile float* red) {
#pragma unroll
    for (int off = 32; off >= 1; off >>= 1) v += __shfl_xor(v, off, 64);
    int wid = threadIdx.x >> 6;
    __syncthreads();                       // protect red reuse across calls
    if ((threadIdx.x & 63) == 0) red[wid] = v;
    __syncthreads();
    return red[0] + red[1] + red[2] + red[3];
}

// ---------------------------------------------------------------------------
// fp32 -> bf16 convert (n4 = number of float4 groups)
// ---------------------------------------------------------------------------
__global__ __launch_bounds__(256) void convert_bf16_kernel(
    const float* __restrict__ in, unsigned short* __restrict__ out, int n4)
{
    int i = blockIdx.x * 256 + threadIdx.x;
    if (i >= n4) return;
    float4 v = *(const float4*)&in[(size_t)i * 4];
    us4 o = { f2bf(v.x), f2bf(v.y), f2bf(v.z), f2bf(v.w) };
    *(us4*)&out[(size_t)i * 4] = o;
}

// ---------------------------------------------------------------------------
// bf16 MFMA GEMM: Y[N][M] = A[N][lda(bf16)] @ W[M][K]^T + bias[M], fp32 out.
// 128x128 tile / 256 threads (4 waves, 2x2), BK=32, mfma 16x16x32 bf16.
// ---------------------------------------------------------------------------
__global__ __launch_bounds__(256) void gemm_bf16_kernel(
    const unsigned short* __restrict__ A,
    const unsigned short* __restrict__ W,
    const float* __restrict__ bias,
    float* __restrict__ Y,
    int M, int K, int lda)
{
    __shared__ unsigned short As[128 * 32];
    __shared__ unsigned short Bs[128 * 32];

    const int t    = threadIdx.x;
    const int lane = t & 63;
    const int w    = t >> 6;
    const int wr   = w >> 1, wc = w & 1;
    const int i0   = blockIdx.y * 128;
    const int j0   = blockIdx.x * 128;
    const int lrow = lane & 15;
    const int lk   = (lane >> 4) * 8;

    f32x4 zero4 = {0.f, 0.f, 0.f, 0.f};
    f32x4 acc[4][4];
#pragma unroll
    for (int mi = 0; mi < 4; ++mi)
#pragma unroll
        for (int ni = 0; ni < 4; ++ni) acc[mi][ni] = zero4;

    for (int k0 = 0; k0 < K; k0 += 32) {
#pragma unroll
        for (int s = 0; s < 2; ++s) {
            int u     = s * 4 + w;          // 0..7
            int chunk = u * 64 + lane;      // 0..511 (16B chunks)
            int row   = chunk >> 2;         // 0..127
            int kc    = (chunk & 3) * 8;    // bf16 col offset
            gload_lds16(&A[(size_t)(i0 + row) * lda + k0 + kc], &As[u * 512]);
            gload_lds16(&W[(size_t)(j0 + row) * (size_t)K + k0 + kc], &Bs[u * 512]);
        }
        __syncthreads();

        short8 af[4], bf[4];
#pragma unroll
        for (int mi = 0; mi < 4; ++mi)
            af[mi] = *(const short8*)&As[(wr * 64 + mi * 16 + lrow) * 32 + lk];
#pragma unroll
        for (int ni = 0; ni < 4; ++ni)
            bf[ni] = *(const short8*)&Bs[(wc * 64 + ni * 16 + lrow) * 32 + lk];
#pragma unroll
        for (int mi = 0; mi < 4; ++mi)
#pragma unroll
            for (int ni = 0; ni < 4; ++ni)
                acc[mi][ni] = __builtin_amdgcn_mfma_f32_16x16x32_bf16(
                    af[mi], bf[ni], acc[mi][ni], 0, 0, 0);
        __syncthreads();
    }

    const int orow = (lane >> 4) * 4;
    const int ocol = lane & 15;
#pragma unroll
    for (int ni = 0; ni < 4; ++ni) {
        int c = j0 + wc * 64 + ni * 16 + ocol;
        float bv = bias[c];
#pragma unroll
        for (int mi = 0; mi < 4; ++mi) {
            int rbase = i0 + wr * 64 + mi * 16 + orow;
#pragma unroll
            for (int r = 0; r < 4; ++r)
                Y[(size_t)(rbase + r) * M + c] = acc[mi][ni][r] + bv;
        }
    }
}

// ---------------------------------------------------------------------------
// In-place row normalization: y = y / (||y|| + 1e-8), optional relu AFTER.
// BF16OUT: write bf16 in-place at the row start (stride stays M floats).
// hnorm (only M=1024 && BF16OUT): per-head sum of squares of the ROUNDED bf16
// values, layout [16][BATCH][SEQ] (idx = h*NTOK + (row&1)*SEQ + (row>>1)).
// ---------------------------------------------------------------------------
template<int M, bool RELU, bool BF16OUT>
__global__ __launch_bounds__(256) void rownorm_kernel(float* __restrict__ Y,
                                                      float* __restrict__ hnorm)
{
    __shared__ float red[4];
    const int row = blockIdx.x;
    const int t = threadIdx.x;
    constexpr int NV = M / 1024;        // float4s per thread (1 or 4)
    const size_t base = (size_t)row * M;
    float4 vv[NV];
    float ss = 0.f;
#pragma unroll
    for (int u = 0; u < NV; ++u) {
        vv[u] = *(const float4*)&Y[base + (size_t)(u * 256 + t) * 4];
        ss += vv[u].x*vv[u].x + vv[u].y*vv[u].y + vv[u].z*vv[u].z + vv[u].w*vv[u].w;
    }
    ss = block_sum_256(ss, red);        // barrier: all reads done before writes
    float sc = 1.f / (sqrtf(ss) + 1e-8f);
#pragma unroll
    for (int u = 0; u < NV; ++u) {
        float4 o;
        o.x = vv[u].x * sc; o.y = vv[u].y * sc;
        o.z = vv[u].z * sc; o.w = vv[u].w * sc;
        if (RELU) {
            o.x = fmaxf(o.x, 0.f); o.y = fmaxf(o.y, 0.f);
            o.z = fmaxf(o.z, 0.f); o.w = fmaxf(o.w, 0.f);
        }
        if (BF16OUT) {
            unsigned short* yb = (unsigned short*)&Y[base];
            us4 ob = { f2bf(o.x), f2bf(o.y), f2bf(o.z), f2bf(o.w) };
            *(us4*)&yb[(size_t)(u * 256 + t) * 4] = ob;
            if (M == 1024 && hnorm) {
                // per-head norm of rounded values; head = t/16 (16 thr/head)
                float a0 = bf2f(ob.x), a1 = bf2f(ob.y);
                float a2 = bf2f(ob.z), a3 = bf2f(ob.w);
                float hs = a0*a0 + a1*a1 + a2*a2 + a3*a3;
                hs += __shfl_xor(hs, 1, 16);
                hs += __shfl_xor(hs, 2, 16);
                hs += __shfl_xor(hs, 4, 16);
                hs += __shfl_xor(hs, 8, 16);
                if ((t & 15) == 0)
                    hnorm[(t >> 4) * NTOK + (row & 1) * SEQ + (row >> 1)] = hs;
            }
        } else {
            *(float4*)&Y[base + (size_t)(u * 256 + t) * 4] = o;
        }
    }
}

// ---------------------------------------------------------------------------
// MFMA UHG flash attention, v2.
// Fixed softmax max (scores in [-1,0] by Cauchy-Schwarz on the same bf16
// q/k used for dots and norms): p = exp(s), no online rescale, l summed
// per-lane and reduced once at the end. qn/kn precomputed ([16][B][S]).
// Q fragments in registers (loop-invariant). LDS: Ks+Vt+Ps = 36 KB ->
// 4 blocks/CU. Block 256 thr (4 waves) = 128 Q rows; KV tiles of 64.
// ---------------------------------------------------------------------------
__global__ __launch_bounds__(256, 4) void attn_mfma_kernel(
    const unsigned short* __restrict__ q,
    const unsigned short* __restrict__ k,
    const unsigned short* __restrict__ v,
    const float* __restrict__ qn_g,
    const float* __restrict__ kn_g,
    unsigned short* __restrict__ out)
{
    __shared__ unsigned short Ks[64 * 72];    // [key][dim], pad 72
    __shared__ unsigned short Vt[64 * 72];    // [dim][key], pad 72
    __shared__ unsigned short Ps[4][32 * 72]; // per-wave P [qrow][key]

    const int h = blockIdx.y, b = blockIdx.z;
    const int iq0 = blockIdx.x * 128;
    const int t = threadIdx.x;
    const int lane = t & 63;
    const int w = t >> 6;
    const int lrow = lane & 15;
    const int lk = (lane >> 4) * 8;
    const int g = lane >> 4;
    const int c = lane & 15;
    const int cb = h * HDIM;

    // ---- Q fragments in registers (rows w*32+mi*16+lrow, dims ks*32+lk) ----
    short8 qfrag[2][2];
#pragma unroll
    for (int mi = 0; mi < 2; ++mi)
#pragma unroll
        for (int ks = 0; ks < 2; ++ks) {
            int s = iq0 + w * 32 + mi * 16 + lrow;
            qfrag[mi][ks] = *(const short8*)&q[(size_t)(s * BATCH + b) * 2048 + cb + ks * 32 + lk];
        }
    // ---- qn for this thread's 8 output rows ----
    const float* qnb = qn_g + h * NTOK + b * SEQ;
    const float* knb = kn_g + h * NTOK + b * SEQ;
    float qn_r[2][4];
#pragma unroll
    for (int mi = 0; mi < 2; ++mi)
#pragma unroll
        for (int r = 0; r < 4; ++r)
            qn_r[mi][r] = qnb[iq0 + w * 32 + mi * 16 + g * 4 + r];

    f32x4 zero4 = {0.f, 0.f, 0.f, 0.f};
    f32x4 acc_o[2][4];
    float l_run[2][4];
#pragma unroll
    for (int mi = 0; mi < 2; ++mi)
#pragma unroll
        for (int ni = 0; ni < 4; ++ni) acc_o[mi][ni] = zero4;
#pragma unroll
    for (int mi = 0; mi < 2; ++mi)
#pragma unroll
        for (int r = 0; r < 4; ++r) l_run[mi][r] = 0.f;

    for (int jt = 0; jt < SEQ / 64; ++jt) {
        const int jk0 = jt * 64;
        __syncthreads();    // prev tile's Ks/Vt reads done
        // ---- stage K (64 rows, 8 thr/row, 2 passes, b128) ----
        {
            const int rl = t >> 3, ch = (t & 7) * 8;
#pragma unroll
            for (int p = 0; p < 2; ++p) {
                int row = p * 32 + rl;
                size_t ga = (size_t)((jk0 + row) * BATCH + b) * 2048 + cb + ch;
                *(short8*)&Ks[row * 72 + ch] = *(const short8*)&k[ga];
            }
        }
        // ---- stage V transposed, b32 pair writes: kp=key pair, dc=4-dim grp ----
        {
            const int kp = t & 15, dc = t >> 4;
#pragma unroll
            for (int p = 0; p < 2; ++p) {
                int key0 = p * 32 + kp * 2;
                size_t ga0 = (size_t)((jk0 + key0) * BATCH + b) * 2048 + cb + dc * 4;
                us4 v0 = *(const us4*)&v[ga0];
                us4 v1 = *(const us4*)&v[ga0 + 2 * 2048];
#pragma unroll
                for (int e = 0; e < 4; ++e) {
                    unsigned pk = (unsigned)v0[e] | ((unsigned)v1[e] << 16);
                    *(unsigned*)&Vt[(dc * 4 + e) * 72 + p * 32 + kp * 2] = pk;
                }
            }
        }
        __syncthreads();    // staging visible

        // ---- kn for this lane's 4 columns (L2-resident array) ----
        float kn_c[4];
#pragma unroll
        for (int ni = 0; ni < 4; ++ni)
            kn_c[ni] = knb[jk0 + ni * 16 + c];

        // ---- QK^T ----
        f32x4 sc[2][4];
#pragma unroll
        for (int mi = 0; mi < 2; ++mi)
#pragma unroll
            for (int ni = 0; ni < 4; ++ni) sc[mi][ni] = zero4;
#pragma unroll
        for (int ks = 0; ks < 2; ++ks) {
            short8 bk_[4];
#pragma unroll
            for (int ni = 0; ni < 4; ++ni)
                bk_[ni] = *(const short8*)&Ks[(ni * 16 + lrow) * 72 + ks * 32 + lk];
#pragma unroll
            for (int mi = 0; mi < 2; ++mi)
#pragma unroll
                for (int ni = 0; ni < 4; ++ni)
                    sc[mi][ni] = __builtin_amdgcn_mfma_f32_16x16x32_bf16(
                        qfrag[mi][ks], bk_[ni], sc[mi][ni], 0, 0, 0);
        }

        // ---- score transform, p = exp(s) (s in [-1,0], fixed max 0) ----
#pragma unroll
        for (int mi = 0; mi < 2; ++mi)
#pragma unroll
            for (int r = 0; r < 4; ++r) {
                const float qn_i = qn_r[mi][r];
#pragma unroll
                for (int ni = 0; ni < 4; ++ni) {
                    float dot = sc[mi][ni][r];
                    float den = qn_i * kn_c[ni] + 1e-8f;
                    float quad = fmaxf(den - dot * dot, 0.f);
                    float sv = -sqrtf(quad) * rsqrtf(den);
                    float p = __expf(sv);
                    l_run[mi][r] += p;
                    Ps[w][(mi * 16 + g * 4 + r) * 72 + ni * 16 + c] = f2bf(p);
                }
            }

        // ---- PV: O += P @ V (A=own-wave P, B=Vt rows = dims) ----
#pragma unroll
        for (int ks = 0; ks < 2; ++ks) {
            short8 ap[2], bv_[4];
#pragma unroll
            for (int mi = 0; mi < 2; ++mi)
                ap[mi] = *(const short8*)&Ps[w][(mi * 16 + lrow) * 72 + ks * 32 + lk];
#pragma unroll
            for (int ni = 0; ni < 4; ++ni)
                bv_[ni] = *(const short8*)&Vt[(ni * 16 + lrow) * 72 + ks * 32 + lk];
#pragma unroll
            for (int mi = 0; mi < 2; ++mi)
#pragma unroll
                for (int ni = 0; ni < 4; ++ni)
                    acc_o[mi][ni] = __builtin_amdgcn_mfma_f32_16x16x32_bf16(
                        ap[mi], bv_[ni], acc_o[mi][ni], 0, 0, 0);
        }
    }

    // ---- final l reduction (cols spread over the 16-lane row group) ----
#pragma unroll
    for (int mi = 0; mi < 2; ++mi)
#pragma unroll
        for (int r = 0; r < 4; ++r) {
            float lv = l_run[mi][r];
            lv += __shfl_xor(lv, 1, 16);
            lv += __shfl_xor(lv, 2, 16);
            lv += __shfl_xor(lv, 4, 16);
            lv += __shfl_xor(lv, 8, 16);
            float inv = 1.f / lv;
            int qs = iq0 + w * 32 + mi * 16 + g * 4 + r;
            size_t ob = (size_t)(qs * BATCH + b) * 1024 + cb;
#pragma unroll
            for (int ni = 0; ni < 4; ++ni)
                out[ob + ni * 16 + c] = f2bf(acc_o[mi][ni][r] * inv);
        }
}

// ---------------------------------------------------------------------------
// y = LayerNorm(A + B; ddof=1, eps=1e-5) * g + beta ; if FINAL: y /= ||y||
// optional bf16 copy to Yb (dense, stride D_MODEL). one block per row.
// ---------------------------------------------------------------------------
__global__ __launch_bounds__(256) void add_ln_kernel(
    const float* __restrict__ A, const float* __restrict__ Bp,
    const float* __restrict__ g, const float* __restrict__ beta,
    float* __restrict__ Y, unsigned short* __restrict__ Yb, int finalnorm)
{
    __shared__ float red[4];
    const int row = blockIdx.x;
    const int t = threadIdx.x;
    const size_t base = (size_t)row * D_MODEL + t * 4;

    float4 a = *(const float4*)&A[base];
    float4 c = *(const float4*)&Bp[base];
    float4 vx = {a.x + c.x, a.y + c.y, a.z + c.z, a.w + c.w};

    float s = vx.x + vx.y + vx.z + vx.w;
    s = block_sum_256(s, red);
    float mean = s * (1.f / 1024.f);

    float4 dv = {vx.x - mean, vx.y - mean, vx.z - mean, vx.w - mean};
    float s2 = dv.x*dv.x + dv.y*dv.y + dv.z*dv.z + dv.w*dv.w;
    s2 = block_sum_256(s2, red);
    float rstd = rsqrtf(s2 * (1.f / 1023.f) + 1e-5f);

    float4 gg = *(const float4*)&g[t * 4];
    float4 bb = *(const float4*)&beta[t * 4];
    float4 y;
    y.x = dv.x * rstd * gg.x + bb.x;
    y.y = dv.y * rstd * gg.y + bb.y;
    y.z = dv.z * rstd * gg.z + bb.z;
    y.w = dv.w * rstd * gg.w + bb.w;

    if (finalnorm) {
        float s3 = y.x*y.x + y.y*y.y + y.z*y.z + y.w*y.w;
        s3 = block_sum_256(s3, red);
        float inv = 1.f / sqrtf(s3);
        y.x *= inv; y.y *= inv; y.z *= inv; y.w *= inv;
    }
    *(float4*)&Y[base] = y;
    if (Yb) {
        us4 ob = { f2bf(y.x), f2bf(y.y), f2bf(y.z), f2bf(y.w) };
        *(us4*)&Yb[base] = ob;
    }
}

// ---------------------------------------------------------------------------
extern "C" void kernel_launch(void* const* d_in, const int* in_sizes, int n_in,
                              void* d_out, int out_size, void* d_ws, size_t ws_size,
                              hipStream_t stream)
{
    const float* src  = (const float*)d_in[0];
    const float* wq   = (const float*)d_in[1];
    const float* bq   = (const float*)d_in[2];
    const float* wk   = (const float*)d_in[3];
    const float* bk   = (const float*)d_in[4];
    const float* wv   = (const float*)d_in[5];
    const float* bv   = (const float*)d_in[6];
    const float* wo   = (const float*)d_in[7];
    const float* bo   = (const float*)d_in[8];
    const float* w1   = (const float*)d_in[9];
    const float* b1   = (const float*)d_in[10];
    const float* w2   = (const float*)d_in[11];
    const float* b2   = (const float*)d_in[12];
    const float* g1   = (const float*)d_in[13];
    const float* be1  = (const float*)d_in[14];
    const float* g2   = (const float*)d_in[15];
    const float* be2  = (const float*)d_in[16];

    char* wsb = (char*)d_ws;
    const size_t MB = (size_t)1 << 20;
    float* qb = (float*)(wsb + 0 * MB);      // q (bf16 in-place) -> later x fp32
    float* kb = (float*)(wsb + 16 * MB);     // k ; hb spans [16,80MB)
    float* vb = (float*)(wsb + 32 * MB);     // v
    float* pb = (float*)(wsb + 48 * MB);     // wo projection fp32 (after attn)
    float* qn_g = (float*)(wsb + 48 * MB);   // [16][2][2048] 256KB, dead once
    float* kn_g = (float*)(wsb + 48 * MB + 256 * 1024);  // attn done (pb reuses)
    float* xb = qb;
    float* hb = kb;                          // [16,80MB) fp32 h
    unsigned short* srcb = (unsigned short*)(wsb + 64 * MB);  // 8MB
    unsigned short* abb  = (unsigned short*)(wsb + 72 * MB);  // 8MB attn-out bf16
    unsigned short* wqb  = (unsigned short*)(wsb + 80 * MB);
    unsigned short* wkb  = (unsigned short*)(wsb + 82 * MB);
    unsigned short* wvb  = (unsigned short*)(wsb + 84 * MB);
    unsigned short* wob  = (unsigned short*)(wsb + 86 * MB);
    unsigned short* w1b  = (unsigned short*)(wsb + 88 * MB);  // 8MB
    unsigned short* w2b  = (unsigned short*)(wsb + 96 * MB);  // 8MB
    unsigned short* xbb  = (unsigned short*)(wsb + 104 * MB); // 8MB (peak 112MB)
    unsigned short* hbb  = (unsigned short*)hb;               // in-place, 8192
    unsigned short* qb16 = (unsigned short*)qb;               // in-place, 2048
    unsigned short* kb16 = (unsigned short*)kb;
    unsigned short* vb16 = (unsigned short*)vb;
    float* ffb  = (float*)d_out;
    float* outp = (float*)d_out;

    dim3 blk(256);
    dim3 gP(D_MODEL / 128, NTOK / 128);      // (8,32)  projections
    dim3 gF(D_FF / 128, NTOK / 128);         // (32,32) FFN1

    // ---- fp32 -> bf16 converts (weights + src) ----
    convert_bf16_kernel<<<(NTOK*D_MODEL/4 + 255)/256, blk, 0, stream>>>(src, srcb, NTOK*D_MODEL/4);
    convert_bf16_kernel<<<(D_MODEL*D_MODEL/4 + 255)/256, blk, 0, stream>>>(wq, wqb, D_MODEL*D_MODEL/4);
    convert_bf16_kernel<<<(D_MODEL*D_MODEL/4 + 255)/256, blk, 0, stream>>>(wk, wkb, D_MODEL*D_MODEL/4);
    convert_bf16_kernel<<<(D_MODEL*D_MODEL/4 + 255)/256, blk, 0, stream>>>(wv, wvb, D_MODEL*D_MODEL/4);
    convert_bf16_kernel<<<(D_MODEL*D_MODEL/4 + 255)/256, blk, 0, stream>>>(wo, wob, D_MODEL*D_MODEL/4);
    convert_bf16_kernel<<<(D_FF*D_MODEL/4 + 255)/256, blk, 0, stream>>>(w1, w1b, D_FF*D_MODEL/4);
    convert_bf16_kernel<<<(D_MODEL*D_FF/4 + 255)/256, blk, 0, stream>>>(w2, w2b, D_MODEL*D_FF/4);

    // ---- q, k, v projections + project-to-sphere (bf16 in-place out) ----
    gemm_bf16_kernel<<<gP, blk, 0, stream>>>(srcb, wqb, bq, qb, D_MODEL, D_MODEL, D_MODEL);
    rownorm_kernel<D_MODEL, false, true><<<NTOK, blk, 0, stream>>>(qb, qn_g);
    gemm_bf16_kernel<<<gP, blk, 0, stream>>>(srcb, wkb, bk, kb, D_MODEL, D_MODEL, D_MODEL);
    rownorm_kernel<D_MODEL, false, true><<<NTOK, blk, 0, stream>>>(kb, kn_g);
    gemm_bf16_kernel<<<gP, blk, 0, stream>>>(srcb, wvb, bv, vb, D_MODEL, D_MODEL, D_MODEL);
    rownorm_kernel<D_MODEL, false, true><<<NTOK, blk, 0, stream>>>(vb, nullptr);

    // ---- attention (bf16 MFMA, fixed-max softmax), writes bf16 ----
    attn_mfma_kernel<<<dim3(SEQ / 128, N_HEADS, BATCH), blk, 0, stream>>>(
        qb16, kb16, vb16, qn_g, kn_g, abb);

    // ---- output projection ----
    gemm_bf16_kernel<<<gP, blk, 0, stream>>>(abb, wob, bo, pb, D_MODEL, D_MODEL, D_MODEL);
    rownorm_kernel<D_MODEL, false, false><<<NTOK, blk, 0, stream>>>(pb, nullptr);

    // ---- x = LN(src + attn_out), fp32 + bf16 copy ----
    add_ln_kernel<<<NTOK, blk, 0, stream>>>(src, pb, g1, be1, xb, xbb, 0);

    // ---- FFN ----
    gemm_bf16_kernel<<<gF, blk, 0, stream>>>(xbb, w1b, b1, hb, D_FF, D_MODEL, D_MODEL);
    rownorm_kernel<D_FF, true, true><<<NTOK, blk, 0, stream>>>(hb, nullptr);
    gemm_bf16_kernel<<<gP, blk, 0, stream>>>(hbb, w2b, b2, ffb, D_MODEL, D_FF, 2 * D_FF);
    rownorm_kernel<D_MODEL, false, false><<<NTOK, blk, 0, stream>>>(ffb, nullptr);

    // ---- x = LN(x + ff); x /= ||x|| ----
    add_ln_kernel<<<NTOK, blk, 0, stream>>>(xb, ffb, g2, be2, outp, nullptr, 1);
}